// Round 7
// baseline (220.345 us; speedup 1.0000x reference)
//
#include <hip/hip_runtime.h>

// SwitchTransformers sparse MLP (top-1 MoE), MI355X/gfx950.
// Round 7: cross-tile register-pipelined GEMM. Ring-4 LDS slots staged 3
// tiles ahead (counted vmcnt(4), never 0 until tail), fragments for tile
// t+1 pre-read from LDS during tile t's MFMA clusters -> ds_read fully
// overlaps MFMA (was serialized: ~1000 + 1242 cyc/step). Router/scan/copy/
// convT/reduce unchanged from round 6.

typedef __attribute__((ext_vector_type(4))) float f32x4;
typedef __attribute__((ext_vector_type(8))) short short8;
typedef unsigned short ushort_t;
typedef unsigned int uint32;

#define DEVFN static __device__ __forceinline__
#define MFMA __builtin_amdgcn_mfma_f32_16x16x32_bf16

constexpr int NTOK = 4096;
constexpr int DM   = 768;
constexpr int DF   = 3072;
constexpr int NE   = 8;
constexpr int TM   = 256;                  // row-tile granule
constexpr int MAXTILES = NTOK / TM + NE;   // 24
constexpr int MAXR  = MAXTILES * TM;       // 6144
constexpr int BK    = 32;
constexpr int NKT   = 768 / BK;            // 24 K-steps (even)

// meta ints: [8..15] segStart, [16..23] seg_end, [24] nTiles,
// [64..87] tileExpert, [128..151] tileRow
DEVFN ushort_t f2bf(float f) {
  uint32 u = __float_as_uint(f);
  u += 0x7fffu + ((u >> 16) & 1u);
  return (ushort_t)(u >> 16);
}
DEVFN float bf2f(ushort_t u) { return __uint_as_float((uint32)u << 16); }

DEVFN void gl16(const void* g, void* l) {   // 16B/lane direct-to-LDS
  __builtin_amdgcn_global_load_lds(
      (const __attribute__((address_space(1))) void*)g,
      (__attribute__((address_space(3))) void*)l, 16, 0, 0);
}

// One wave per token: fp64 logits (argmax robustness), fp32 softmax
// computed redundantly on all lanes (no divergent fp64 exp, no atomics).
__global__ __launch_bounds__(256) void k_router(
    const float* __restrict__ X, const float* __restrict__ Wr,
    float* __restrict__ out_logits, float* __restrict__ out_idx,
    int* __restrict__ expert_of, float* __restrict__ prob) {
  int wid = threadIdx.x >> 6, lane = threadIdx.x & 63;
  int t = blockIdx.x * 4 + wid;
  const float* xrow = X + (size_t)t * DM;
  double acc[NE];
#pragma unroll
  for (int e = 0; e < NE; e++) acc[e] = 0.0;
  for (int d0 = 0; d0 < DM; d0 += 64) {
    int d = d0 + lane;
    float x = xrow[d];
    const float4* w4 = (const float4*)(Wr + (size_t)d * NE);
    float4 wa = w4[0], wb = w4[1];
    acc[0] += (double)x * wa.x; acc[1] += (double)x * wa.y;
    acc[2] += (double)x * wa.z; acc[3] += (double)x * wa.w;
    acc[4] += (double)x * wb.x; acc[5] += (double)x * wb.y;
    acc[6] += (double)x * wb.z; acc[7] += (double)x * wb.w;
  }
#pragma unroll
  for (int e = 0; e < NE; e++) {
#pragma unroll
    for (int s = 32; s > 0; s >>= 1) acc[e] += __shfl_xor(acc[e], s);
  }
#pragma unroll
  for (int e = 0; e < NE; e++)
    if (lane == e) out_logits[(size_t)t * NE + e] = (float)acc[e];
  double m = acc[0]; int idx = 0;
#pragma unroll
  for (int e = 1; e < NE; e++) if (acc[e] > m) { m = acc[e]; idx = e; }
  float s = 0.f;
#pragma unroll
  for (int e = 0; e < NE; e++) s += expf((float)(acc[e] - m));
  if (lane == 0) {
    out_idx[t] = (float)idx;
    expert_of[t] = idx;
    prob[t] = 1.f / s;
  }
}

// Single-block scan: per-group counts, per-expert exclusive scan, padded
// segment layout + tile table, stable-order scatter. Deterministic.
__global__ __launch_bounds__(64) void k_scan(
    const int* __restrict__ expert_of, const float* __restrict__ prob,
    int* __restrict__ meta, int* __restrict__ perm,
    float* __restrict__ prob_g) {
  __shared__ int exl[NTOK];
  int lane = threadIdx.x;
  const int4* src = (const int4*)expert_of;
  int4* dst = (int4*)exl;
#pragma unroll
  for (int j = 0; j < NTOK / 4 / 64; j++) dst[j * 64 + lane] = src[j * 64 + lane];
  __syncthreads();
  int cnt[NE];
#pragma unroll
  for (int e = 0; e < NE; e++) cnt[e] = 0;
  for (int j = 0; j < 64; j++) {
    int ex = exl[lane * 64 + j];
#pragma unroll
    for (int e = 0; e < NE; e++) cnt[e] += (ex == e);
  }
  int base[NE], tot[NE];
#pragma unroll
  for (int e = 0; e < NE; e++) {
    int inc = cnt[e];
#pragma unroll
    for (int s = 1; s < 64; s <<= 1) {
      int o = __shfl_up(inc, s);
      if (lane >= s) inc += o;
    }
    base[e] = inc - cnt[e];
    tot[e] = __shfl(inc, 63);
  }
  int segStart[NE];
  int pos = 0, nt = 0;
#pragma unroll
  for (int e = 0; e < NE; e++) {
    segStart[e] = pos;
    int tiles = (tot[e] + TM - 1) / TM;
    if (lane == 0) {
      meta[8 + e] = pos;
      meta[16 + e] = pos + tot[e];
      for (int i = 0; i < tiles; i++) {
        meta[64 + nt + i] = e;
        meta[128 + nt + i] = pos + i * TM;
      }
    }
    nt += tiles;
    pos += tiles * TM;
  }
  if (lane == 0) meta[24] = nt;
  int cum[NE];
#pragma unroll
  for (int e = 0; e < NE; e++) cum[e] = segStart[e] + base[e];
  for (int j = 0; j < 64; j++) {
    int t = lane * 64 + j;
    int ex = exl[lane * 64 + j];
    int p = 0;
#pragma unroll
    for (int e = 0; e < NE; e++) p += (ex == e) ? cum[e] : 0;
#pragma unroll
    for (int e = 0; e < NE; e++) cum[e] += (ex == e);
    perm[p] = t;
    prob_g[p] = prob[t];
  }
}

// Destination-indexed gather: Xg[r] = bf16(X[perm[r]]) for valid rows.
__global__ __launch_bounds__(256) void k_copy(
    const float* __restrict__ X, const int* __restrict__ meta,
    const int* __restrict__ perm, ushort_t* __restrict__ Xg) {
  int bt = blockIdx.x;
  if (bt >= meta[24]) return;
  int e = meta[64 + bt], row0 = meta[128 + bt], segEnd = meta[16 + e];
  int wid = threadIdx.x >> 6, lane = threadIdx.x & 63;
  int r = row0 + blockIdx.y * 4 + wid;
  if (r >= segEnd) return;
  int tok = perm[r];
  const float2* s2 = (const float2*)(X + (size_t)tok * DM);
  uint32* d2 = (uint32*)(Xg + (size_t)r * DM);
#pragma unroll
  for (int i = 0; i < DM / 128; i++) {
    float2 v = s2[i * 64 + lane];
    d2[i * 64 + lane] = (uint32)f2bf(v.x) | ((uint32)f2bf(v.y) << 16);
  }
}

// Convert + transpose: W [E][R][C] fp32 -> WT [E][C][R] bf16. 128x128 tiles.
__global__ __launch_bounds__(256) void k_convT(
    const float* __restrict__ W, ushort_t* __restrict__ WT, int R, int C) {
  __shared__ ushort_t T[128][136];
  int e = blockIdx.z;
  int r0 = blockIdx.x * 128, c0 = blockIdx.y * 128;
  const float* src = W + ((size_t)e * R + r0) * C + c0;
  int t = threadIdx.x;
  int lr = t >> 1, cc = (t & 1) * 64;
#pragma unroll
  for (int j = 0; j < 16; j++) {
    float4 v = *(const float4*)(src + (size_t)lr * C + cc + j * 4);
    T[cc + j * 4 + 0][lr] = f2bf(v.x);
    T[cc + j * 4 + 1][lr] = f2bf(v.y);
    T[cc + j * 4 + 2][lr] = f2bf(v.z);
    T[cc + j * 4 + 3][lr] = f2bf(v.w);
  }
  __syncthreads();
  ushort_t* dst = WT + ((size_t)e * C + c0) * R + r0;
  int lc = t >> 1, rr = (t & 1) * 64;
#pragma unroll
  for (int j = 0; j < 8; j++)
    *(short8*)(dst + (size_t)lc * R + rr + j * 8) =
        *(const short8*)&T[lc][rr + j * 8];
}

// ---------------------------------------------------------------------------
// 8-wave 256x256 GEMM, BK=32, ring-4 LDS slots staged 3 tiles ahead,
// counted vmcnt(4) + 1 barrier per K-tile, XOR bank swizzle, cross-tile
// register double-buffering: tile t+1's m0-3/B fragments are ds_read during
// tile t's MFMA clusters. Per-wave output 128x64 (waves 2Mx4N).
// ---------------------------------------------------------------------------
template <int LDA, int NB, bool FIRST>
__global__ __launch_bounds__(512, 2) void k_gemm8(
    const ushort_t* __restrict__ A, const ushort_t* __restrict__ BT,
    const int* __restrict__ meta, ushort_t* __restrict__ Obf) {
  __shared__ short A_lds[4][256 * BK];
  __shared__ short B_lds[4][256 * BK];

  int bt = blockIdx.x;
  if (bt >= meta[24]) return;      // uniform exit before any barrier
  int e    = meta[64 + bt];
  int row0 = meta[128 + bt];
  int n0   = blockIdx.y * 256;
  int koff = blockIdx.z * 768;

  int tid = threadIdx.x, lane = tid & 63, w = tid >> 6;
  int wr = w >> 2, wc = w & 3;

  // Staging: thread -> row tid>>2, 16B slot tid&3 (linear LDS dest);
  // global source pre-swizzled: kslot_log = (lane&3) ^ ((lane>>3)&3).
  int srcSlot = (lane & 3) ^ ((lane >> 3) & 3);
  const ushort_t* aS = A + (size_t)(row0 + (tid >> 2)) * LDA + koff + srcSlot * 8;
  const ushort_t* bS = BT + ((size_t)e * NB + n0 + (tid >> 2)) * LDA + koff + srcSlot * 8;
  int dstOff = w * 512;   // wave-uniform LDS short offset (16 rows/wave/issue)

#define STAGE_A(sl, kt)                                                      \
  do {                                                                       \
    gl16(aS + (size_t)(kt) * BK, &A_lds[sl][dstOff]);                        \
    gl16(aS + (size_t)(kt) * BK + (size_t)128 * LDA, &A_lds[sl][dstOff + 4096]); \
  } while (0)
#define STAGE_B(sl, kt)                                                      \
  do {                                                                       \
    gl16(bS + (size_t)(kt) * BK, &B_lds[sl][dstOff]);                        \
    gl16(bS + (size_t)(kt) * BK + (size_t)128 * LDA, &B_lds[sl][dstOff + 4096]); \
  } while (0)

  // Swizzled read offsets: physical kslot = logical ^ ((row>>1)&3).
  int kslotRd = ((lane >> 4) ^ ((lane >> 1) & 3)) * 8;
  int aOff[8], bOff[4];
#pragma unroll
  for (int m = 0; m < 8; m++)
    aOff[m] = (wr * 128 + m * 16 + (lane & 15)) * BK + kslotRd;
#pragma unroll
  for (int n = 0; n < 4; n++)
    bOff[n] = (wc * 64 + n * 16 + (lane & 15)) * BK + kslotRd;

  f32x4 acc[8][4];
#pragma unroll
  for (int m = 0; m < 8; m++)
#pragma unroll
    for (int n = 0; n < 4; n++) acc[m][n] = (f32x4){0.f, 0.f, 0.f, 0.f};

  // Prologue: stage slots 0..2 (12 loads), confirm slot 0, pre-read tile 0.
  STAGE_A(0, 0); STAGE_B(0, 0);
  STAGE_A(1, 1); STAGE_B(1, 1);
  STAGE_A(2, 2); STAGE_B(2, 2);
  asm volatile("s_waitcnt vmcnt(8)" ::: "memory");   // slot 0 done
  __builtin_amdgcn_s_barrier();
  asm volatile("" ::: "memory");
  short8 paA[4], pbA[4], paB[4], pbB[4];
#pragma unroll
  for (int m = 0; m < 4; m++) paA[m] = *(const short8*)&A_lds[0][aOff[m]];
#pragma unroll
  for (int n = 0; n < 4; n++) pbA[n] = *(const short8*)&B_lds[0][bOff[n]];

  // Tile body: PA/PB = this tile's pre-read frags; NA/NB <- next tile's.
#define TILE(T, PA, PB, NA, NB, VM)                                          \
  do {                                                                       \
    asm volatile("s_waitcnt vmcnt(" #VM ")" ::: "memory");                   \
    __builtin_amdgcn_s_barrier();                                            \
    asm volatile("" ::: "memory");                                           \
    __builtin_amdgcn_sched_barrier(0);                                       \
    const short* aB_ = A_lds[(T) & 3];                                       \
    if ((T) + 3 < NKT) STAGE_A(((T) + 3) & 3, (T) + 3);                      \
    short8 c4 = *(const short8*)&aB_[aOff[4]];                               \
    short8 c5 = *(const short8*)&aB_[aOff[5]];                               \
    short8 c6 = *(const short8*)&aB_[aOff[6]];                               \
    short8 c7 = *(const short8*)&aB_[aOff[7]];                               \
    __builtin_amdgcn_s_setprio(1);                                           \
    _Pragma("unroll") for (int n = 0; n < 4; n++) {                          \
      acc[0][n] = MFMA(PA[0], PB[n], acc[0][n], 0, 0, 0);                    \
      acc[1][n] = MFMA(PA[1], PB[n], acc[1][n], 0, 0, 0);                    \
      acc[2][n] = MFMA(PA[2], PB[n], acc[2][n], 0, 0, 0);                    \
      acc[3][n] = MFMA(PA[3], PB[n], acc[3][n], 0, 0, 0);                    \
    }                                                                        \
    __builtin_amdgcn_s_setprio(0);                                           \
    if ((T) + 3 < NKT) STAGE_B(((T) + 3) & 3, (T) + 3);                      \
    if ((T) + 1 < NKT) {                                                     \
      const short* aN_ = A_lds[((T) + 1) & 3];                               \
      const short* bN_ = B_lds[((T) + 1) & 3];                               \
      _Pragma("unroll") for (int m = 0; m < 4; m++)                          \
        NA[m] = *(const short8*)&aN_[aOff[m]];                               \
      _Pragma("unroll") for (int n = 0; n < 4; n++)                          \
        NB[n] = *(const short8*)&bN_[bOff[n]];                               \
    }                                                                        \
    __builtin_amdgcn_s_setprio(1);                                           \
    _Pragma("unroll") for (int n = 0; n < 4; n++) {                          \
      acc[4][n] = MFMA(c4, PB[n], acc[4][n], 0, 0, 0);                       \
      acc[5][n] = MFMA(c5, PB[n], acc[5][n], 0, 0, 0);                       \
      acc[6][n] = MFMA(c6, PB[n], acc[6][n], 0, 0, 0);                       \
      acc[7][n] = MFMA(c7, PB[n], acc[7][n], 0, 0, 0);                       \
    }                                                                        \
    __builtin_amdgcn_s_setprio(0);                                           \
  } while (0)

  for (int tt = 0; tt < NKT - 2; tt += 2) {
    TILE(tt,     paA, pbA, paB, pbB, 4);
    TILE(tt + 1, paB, pbB, paA, pbA, 4);
  }
  TILE(NKT - 2, paA, pbA, paB, pbB, 0);
  TILE(NKT - 1, paB, pbB, paA, pbA, 0);
#undef TILE
#undef STAGE_A
#undef STAGE_B

  // C/D: col = lane&15, row = (lane>>4)*4 + r
  ushort_t* dst = FIRST ? Obf : Obf + (size_t)blockIdx.z * MAXR * NB;
#pragma unroll
  for (int m = 0; m < 8; m++) {
    int rowb = row0 + wr * 128 + m * 16 + (lane >> 4) * 4;
#pragma unroll
    for (int n = 0; n < 4; n++) {
      int col = n0 + wc * 64 + n * 16 + (lane & 15);
#pragma unroll
      for (int r = 0; r < 4; r++) {
        float v = acc[m][n][r];
        if (FIRST) v = v > 0.f ? v : 0.f;
        dst[(size_t)(rowb + r) * NB + col] = f2bf(v);
      }
    }
  }
}

// Reduce split-K partials, scale by prob, scatter to token rows.
__global__ __launch_bounds__(256) void k_reduce(
    const ushort_t* __restrict__ P, const int* __restrict__ meta,
    const int* __restrict__ perm, const float* __restrict__ prob_g,
    float* __restrict__ out) {
  int bt = blockIdx.x;
  if (bt >= meta[24]) return;
  int e = meta[64 + bt], row0 = meta[128 + bt], segEnd = meta[16 + e];
  int c0 = blockIdx.y * 64;
  int t = threadIdx.x;
  int col = c0 + (t & 7) * 8;
#pragma unroll
  for (int i = 0; i < 8; i++) {
    int r = row0 + (t >> 3) + i * 32;
    if (r >= segEnd) continue;
    int tok = perm[r];
    float p = prob_g[r];
    float s[8];
#pragma unroll
    for (int j = 0; j < 8; j++) s[j] = 0.f;
#pragma unroll
    for (int z = 0; z < 4; z++) {
      short8 v = *(const short8*)&P[((size_t)z * MAXR + r) * DM + col];
#pragma unroll
      for (int j = 0; j < 8; j++) s[j] += bf2f((ushort_t)v[j]);
    }
    float4 o0 = {p * s[0], p * s[1], p * s[2], p * s[3]};
    float4 o1 = {p * s[4], p * s[5], p * s[6], p * s[7]};
    *(float4*)&out[(size_t)tok * DM + col] = o0;
    *(float4*)&out[(size_t)tok * DM + col + 4] = o1;
  }
}

extern "C" void kernel_launch(void* const* d_in, const int* in_sizes, int n_in,
                              void* d_out, int out_size, void* d_ws, size_t ws_size,
                              hipStream_t stream) {
  const float* X  = (const float*)d_in[0];
  const float* Wr = (const float*)d_in[1];
  const float* wi = (const float*)d_in[2];
  const float* wo = (const float*)d_in[3];

  float* out        = (float*)d_out;
  float* out_logits = out + (size_t)NTOK * DM;
  float* out_idx    = out_logits + (size_t)NTOK * NE;

  char* w = (char*)d_ws;
  int*      meta      = (int*)w;                    // 4 KiB
  int*      expert_of = (int*)(w + 4096);           // 16 KiB
  float*    prob      = (float*)(w + 20480);        // 16 KiB
  int*      perm      = (int*)(w + 36864);          // 24 KiB
  float*    prob_g    = (float*)(w + 61440);        // 24 KiB
  ushort_t* Xg        = (ushort_t*)(w + 131072);    // 6144*768 bf16
  ushort_t* H         = Xg + (size_t)MAXR * DM;     // 6144*3072 bf16
  ushort_t* woT       = H + (size_t)MAXR * DF;      // 8*768*3072 bf16
  ushort_t* wiT       = woT + (size_t)NE * DM * DF; // 8*3072*768 bf16
  ushort_t* P         = wiT;                        // alias: wiT dead after GEMM1
  // total ws ~ 123 MB

  k_convT<<<dim3(DM / 128, DF / 128, NE), 256, 0, stream>>>(wi, wiT, DM, DF);
  k_convT<<<dim3(DF / 128, DM / 128, NE), 256, 0, stream>>>(wo, woT, DF, DM);
  k_router<<<NTOK / 4, 256, 0, stream>>>(X, Wr, out_logits, out_idx,
                                         expert_of, prob);
  k_scan<<<1, 64, 0, stream>>>(expert_of, prob, meta, perm, prob_g);
  k_copy<<<dim3(MAXTILES, TM / 4), 256, 0, stream>>>(X, meta, perm, Xg);
  k_gemm8<DM, DF, true><<<dim3(MAXTILES, DF / 256, 1), 512, 0, stream>>>(
      Xg, wiT, meta, H);
  k_gemm8<DF, DM, false><<<dim3(MAXTILES, DM / 256, 4), 512, 0, stream>>>(
      H, woT, meta, P);
  k_reduce<<<dim3(MAXTILES, DM / 64), 256, 0, stream>>>(P, meta, perm, prob_g, out);
}

// Round 8
// 167.609 us; speedup vs baseline: 1.3146x; 1.3146x over previous
//
#include <hip/hip_runtime.h>

// SwitchTransformers sparse MLP (top-1 MoE), MI355X/gfx950.
// Round 8: revert to round-6 GEMM loop (cross-tile reg pipeline regressed);
// live-block compaction: tile index moved to the SLOW grid dim so dead
// blocks form a contiguous tail (was: 2 sequential rounds of blocks, ~2x
// dispatch time). Router/scan/convT/reduce logic unchanged.

typedef __attribute__((ext_vector_type(4))) float f32x4;
typedef __attribute__((ext_vector_type(8))) short short8;
typedef unsigned short ushort_t;
typedef unsigned int uint32;

#define DEVFN static __device__ __forceinline__
#define MFMA __builtin_amdgcn_mfma_f32_16x16x32_bf16

constexpr int NTOK = 4096;
constexpr int DM   = 768;
constexpr int DF   = 3072;
constexpr int NE   = 8;
constexpr int TM   = 256;                  // row-tile granule
constexpr int MAXTILES = NTOK / TM + NE;   // 24
constexpr int MAXR  = MAXTILES * TM;       // 6144
constexpr int BK    = 32;
constexpr int NKT   = 768 / BK;            // 24 K-steps per (split-)GEMM

// meta ints: [8..15] segStart, [16..23] seg_end, [24] nTiles,
// [64..87] tileExpert, [128..151] tileRow
DEVFN ushort_t f2bf(float f) {
  uint32 u = __float_as_uint(f);
  u += 0x7fffu + ((u >> 16) & 1u);
  return (ushort_t)(u >> 16);
}
DEVFN float bf2f(ushort_t u) { return __uint_as_float((uint32)u << 16); }

DEVFN void gl16(const void* g, void* l) {   // 16B/lane direct-to-LDS
  __builtin_amdgcn_global_load_lds(
      (const __attribute__((address_space(1))) void*)g,
      (__attribute__((address_space(3))) void*)l, 16, 0, 0);
}

// One wave per token: fp64 logits (argmax robustness), fp32 softmax
// computed redundantly on all lanes (no divergent fp64 exp, no atomics).
__global__ __launch_bounds__(256) void k_router(
    const float* __restrict__ X, const float* __restrict__ Wr,
    float* __restrict__ out_logits, float* __restrict__ out_idx,
    int* __restrict__ expert_of, float* __restrict__ prob) {
  int wid = threadIdx.x >> 6, lane = threadIdx.x & 63;
  int t = blockIdx.x * 4 + wid;
  const float* xrow = X + (size_t)t * DM;
  double acc[NE];
#pragma unroll
  for (int e = 0; e < NE; e++) acc[e] = 0.0;
  for (int d0 = 0; d0 < DM; d0 += 64) {
    int d = d0 + lane;
    float x = xrow[d];
    const float4* w4 = (const float4*)(Wr + (size_t)d * NE);
    float4 wa = w4[0], wb = w4[1];
    acc[0] += (double)x * wa.x; acc[1] += (double)x * wa.y;
    acc[2] += (double)x * wa.z; acc[3] += (double)x * wa.w;
    acc[4] += (double)x * wb.x; acc[5] += (double)x * wb.y;
    acc[6] += (double)x * wb.z; acc[7] += (double)x * wb.w;
  }
#pragma unroll
  for (int e = 0; e < NE; e++) {
#pragma unroll
    for (int s = 32; s > 0; s >>= 1) acc[e] += __shfl_xor(acc[e], s);
  }
#pragma unroll
  for (int e = 0; e < NE; e++)
    if (lane == e) out_logits[(size_t)t * NE + e] = (float)acc[e];
  double m = acc[0]; int idx = 0;
#pragma unroll
  for (int e = 1; e < NE; e++) if (acc[e] > m) { m = acc[e]; idx = e; }
  float s = 0.f;
#pragma unroll
  for (int e = 0; e < NE; e++) s += expf((float)(acc[e] - m));
  if (lane == 0) {
    out_idx[t] = (float)idx;
    expert_of[t] = idx;
    prob[t] = 1.f / s;
  }
}

// Single-block scan: per-group counts, per-expert exclusive scan, padded
// segment layout + tile table, stable-order scatter. Deterministic.
__global__ __launch_bounds__(64) void k_scan(
    const int* __restrict__ expert_of, const float* __restrict__ prob,
    int* __restrict__ meta, int* __restrict__ perm,
    float* __restrict__ prob_g) {
  __shared__ int exl[NTOK];
  int lane = threadIdx.x;
  const int4* src = (const int4*)expert_of;
  int4* dst = (int4*)exl;
#pragma unroll
  for (int j = 0; j < NTOK / 4 / 64; j++) dst[j * 64 + lane] = src[j * 64 + lane];
  __syncthreads();
  int cnt[NE];
#pragma unroll
  for (int e = 0; e < NE; e++) cnt[e] = 0;
  for (int j = 0; j < 64; j++) {
    int ex = exl[lane * 64 + j];
#pragma unroll
    for (int e = 0; e < NE; e++) cnt[e] += (ex == e);
  }
  int base[NE], tot[NE];
#pragma unroll
  for (int e = 0; e < NE; e++) {
    int inc = cnt[e];
#pragma unroll
    for (int s = 1; s < 64; s <<= 1) {
      int o = __shfl_up(inc, s);
      if (lane >= s) inc += o;
    }
    base[e] = inc - cnt[e];
    tot[e] = __shfl(inc, 63);
  }
  int segStart[NE];
  int pos = 0, nt = 0;
#pragma unroll
  for (int e = 0; e < NE; e++) {
    segStart[e] = pos;
    int tiles = (tot[e] + TM - 1) / TM;
    if (lane == 0) {
      meta[8 + e] = pos;
      meta[16 + e] = pos + tot[e];
      for (int i = 0; i < tiles; i++) {
        meta[64 + nt + i] = e;
        meta[128 + nt + i] = pos + i * TM;
      }
    }
    nt += tiles;
    pos += tiles * TM;
  }
  if (lane == 0) meta[24] = nt;
  int cum[NE];
#pragma unroll
  for (int e = 0; e < NE; e++) cum[e] = segStart[e] + base[e];
  for (int j = 0; j < 64; j++) {
    int t = lane * 64 + j;
    int ex = exl[lane * 64 + j];
    int p = 0;
#pragma unroll
    for (int e = 0; e < NE; e++) p += (ex == e) ? cum[e] : 0;
#pragma unroll
    for (int e = 0; e < NE; e++) cum[e] += (ex == e);
    perm[p] = t;
    prob_g[p] = prob[t];
  }
}

// Destination-indexed gather: Xg[r] = bf16(X[perm[r]]) for valid rows.
// Grid: (TM/4, MAXTILES) — tile on the slow dim (live-compact).
__global__ __launch_bounds__(256) void k_copy(
    const float* __restrict__ X, const int* __restrict__ meta,
    const int* __restrict__ perm, ushort_t* __restrict__ Xg) {
  int bt = blockIdx.y;
  if (bt >= meta[24]) return;
  int e = meta[64 + bt], row0 = meta[128 + bt], segEnd = meta[16 + e];
  int wid = threadIdx.x >> 6, lane = threadIdx.x & 63;
  int r = row0 + blockIdx.x * 4 + wid;
  if (r >= segEnd) return;
  int tok = perm[r];
  const float2* s2 = (const float2*)(X + (size_t)tok * DM);
  uint32* d2 = (uint32*)(Xg + (size_t)r * DM);
#pragma unroll
  for (int i = 0; i < DM / 128; i++) {
    float2 v = s2[i * 64 + lane];
    d2[i * 64 + lane] = (uint32)f2bf(v.x) | ((uint32)f2bf(v.y) << 16);
  }
}

// Convert + transpose: W [E][R][C] fp32 -> WT [E][C][R] bf16. 128x128 tiles.
__global__ __launch_bounds__(256) void k_convT(
    const float* __restrict__ W, ushort_t* __restrict__ WT, int R, int C) {
  __shared__ ushort_t T[128][136];
  int e = blockIdx.z;
  int r0 = blockIdx.x * 128, c0 = blockIdx.y * 128;
  const float* src = W + ((size_t)e * R + r0) * C + c0;
  int t = threadIdx.x;
  int lr = t >> 1, cc = (t & 1) * 64;
#pragma unroll
  for (int j = 0; j < 16; j++) {
    float4 v = *(const float4*)(src + (size_t)lr * C + cc + j * 4);
    T[cc + j * 4 + 0][lr] = f2bf(v.x);
    T[cc + j * 4 + 1][lr] = f2bf(v.y);
    T[cc + j * 4 + 2][lr] = f2bf(v.z);
    T[cc + j * 4 + 3][lr] = f2bf(v.w);
  }
  __syncthreads();
  ushort_t* dst = WT + ((size_t)e * C + c0) * R + r0;
  int lc = t >> 1, rr = (t & 1) * 64;
#pragma unroll
  for (int j = 0; j < 8; j++)
    *(short8*)(dst + (size_t)lc * R + rr + j * 8) =
        *(const short8*)&T[lc][rr + j * 8];
}

// ---------------------------------------------------------------------------
// 8-wave 256x256 GEMM, BK=32, ring-4 LDS slots, counted vmcnt(8), 1 barrier
// per K-step, XOR bank swizzle on both operands. Per-wave output 128x64
// (wave grid 2Mx4N), acc[8][4] f32x4, 32 MFMA + 12 ds_read_b128 per K-step.
// Grid: y = row-tile (slow dim: dead blocks form a contiguous tail).
// FIRST: x = N-panel. !FIRST: x = panel*4 + z (split-K, koff = z*768).
// ---------------------------------------------------------------------------
template <int LDA, int NB, bool FIRST>
__global__ __launch_bounds__(512, 2) void k_gemm8(
    const ushort_t* __restrict__ A, const ushort_t* __restrict__ BT,
    const int* __restrict__ meta, ushort_t* __restrict__ Obf) {
  __shared__ short A_lds[4][256 * BK];
  __shared__ short B_lds[4][256 * BK];

  int bt = blockIdx.y;
  if (bt >= meta[24]) return;      // uniform exit before any barrier
  int e    = meta[64 + bt];
  int row0 = meta[128 + bt];
  int n0, koff, z;
  if constexpr (FIRST) {
    n0 = blockIdx.x * 256; koff = 0; z = 0;
  } else {
    n0 = (blockIdx.x >> 2) * 256; z = blockIdx.x & 3; koff = z * 768;
  }

  int tid = threadIdx.x, lane = tid & 63, w = tid >> 6;
  int wr = w >> 2, wc = w & 3;

  // Staging: thread -> row tid>>2, 16B slot tid&3 (linear LDS dest);
  // global source pre-swizzled: kslot_log = (lane&3) ^ ((lane>>3)&3).
  int srcSlot = (lane & 3) ^ ((lane >> 3) & 3);
  const ushort_t* aS = A + (size_t)(row0 + (tid >> 2)) * LDA + koff + srcSlot * 8;
  const ushort_t* bS = BT + ((size_t)e * NB + n0 + (tid >> 2)) * LDA + koff + srcSlot * 8;
  int dstOff = w * 512;   // wave-uniform LDS short offset (16 rows/wave/issue)

#define STAGE(sl, kt)                                                        \
  do {                                                                       \
    gl16(aS + (size_t)(kt) * BK, &A_lds[sl][dstOff]);                        \
    gl16(aS + (size_t)(kt) * BK + (size_t)128 * LDA, &A_lds[sl][dstOff + 4096]); \
    gl16(bS + (size_t)(kt) * BK, &B_lds[sl][dstOff]);                        \
    gl16(bS + (size_t)(kt) * BK + (size_t)128 * LDA, &B_lds[sl][dstOff + 4096]); \
  } while (0)

  // Swizzled read offsets: physical kslot = logical ^ ((row>>1)&3).
  int kslotRd = ((lane >> 4) ^ ((lane >> 1) & 3)) * 8;
  int aOff[8], bOff[4];
#pragma unroll
  for (int m = 0; m < 8; m++)
    aOff[m] = (wr * 128 + m * 16 + (lane & 15)) * BK + kslotRd;
#pragma unroll
  for (int n = 0; n < 4; n++)
    bOff[n] = (wc * 64 + n * 16 + (lane & 15)) * BK + kslotRd;

  f32x4 acc[8][4];
#pragma unroll
  for (int m = 0; m < 8; m++)
#pragma unroll
    for (int n = 0; n < 4; n++) acc[m][n] = (f32x4){0.f, 0.f, 0.f, 0.f};

  STAGE(0, 0); STAGE(1, 1); STAGE(2, 2);   // 12 loads in flight

#pragma unroll 4
  for (int t = 0; t < NKT; ++t) {
    __builtin_amdgcn_sched_barrier(0);
    asm volatile("s_waitcnt vmcnt(8)" ::: "memory");  // own slot-t loads done
    __builtin_amdgcn_s_barrier();                     // all waves' slot-t done;
    asm volatile("" ::: "memory");                    // all done reading t-1
    __builtin_amdgcn_sched_barrier(0);
    int tp = (t + 3 < NKT) ? t + 3 : t;               // dummy keeps vmcnt uniform
    STAGE((t + 3) & 3, tp);                           // (dead ring slot at tail)
    const short* aB = A_lds[t & 3];
    const short* bB = B_lds[t & 3];
    short8 af[8], bf[4];
#pragma unroll
    for (int m = 0; m < 8; m++) af[m] = *(const short8*)&aB[aOff[m]];
#pragma unroll
    for (int n = 0; n < 4; n++) bf[n] = *(const short8*)&bB[bOff[n]];
    __builtin_amdgcn_s_setprio(1);
#pragma unroll
    for (int m = 0; m < 8; m++)
#pragma unroll
      for (int n = 0; n < 4; n++)
        acc[m][n] = MFMA(af[m], bf[n], acc[m][n], 0, 0, 0);
    __builtin_amdgcn_s_setprio(0);
  }
#undef STAGE

  // C/D: col = lane&15, row = (lane>>4)*4 + r
  ushort_t* dst = FIRST ? Obf : Obf + (size_t)z * MAXR * NB;
#pragma unroll
  for (int m = 0; m < 8; m++) {
    int rowb = row0 + wr * 128 + m * 16 + (lane >> 4) * 4;
#pragma unroll
    for (int n = 0; n < 4; n++) {
      int col = n0 + wc * 64 + n * 16 + (lane & 15);
#pragma unroll
      for (int r = 0; r < 4; r++) {
        float v = acc[m][n][r];
        if (FIRST) v = v > 0.f ? v : 0.f;
        dst[(size_t)(rowb + r) * NB + col] = f2bf(v);
      }
    }
  }
}

// Reduce split-K partials, scale by prob, scatter to token rows.
// Grid: (DM/64, MAXTILES) — tile on the slow dim (live-compact).
__global__ __launch_bounds__(256) void k_reduce(
    const ushort_t* __restrict__ P, const int* __restrict__ meta,
    const int* __restrict__ perm, const float* __restrict__ prob_g,
    float* __restrict__ out) {
  int bt = blockIdx.y;
  if (bt >= meta[24]) return;
  int e = meta[64 + bt], row0 = meta[128 + bt], segEnd = meta[16 + e];
  int c0 = blockIdx.x * 64;
  int t = threadIdx.x;
  int col = c0 + (t & 7) * 8;
#pragma unroll
  for (int i = 0; i < 8; i++) {
    int r = row0 + (t >> 3) + i * 32;
    if (r >= segEnd) continue;
    int tok = perm[r];
    float p = prob_g[r];
    float s[8];
#pragma unroll
    for (int j = 0; j < 8; j++) s[j] = 0.f;
#pragma unroll
    for (int z = 0; z < 4; z++) {
      short8 v = *(const short8*)&P[((size_t)z * MAXR + r) * DM + col];
#pragma unroll
      for (int j = 0; j < 8; j++) s[j] += bf2f((ushort_t)v[j]);
    }
    float4 o0 = {p * s[0], p * s[1], p * s[2], p * s[3]};
    float4 o1 = {p * s[4], p * s[5], p * s[6], p * s[7]};
    *(float4*)&out[(size_t)tok * DM + col] = o0;
    *(float4*)&out[(size_t)tok * DM + col + 4] = o1;
  }
}

extern "C" void kernel_launch(void* const* d_in, const int* in_sizes, int n_in,
                              void* d_out, int out_size, void* d_ws, size_t ws_size,
                              hipStream_t stream) {
  const float* X  = (const float*)d_in[0];
  const float* Wr = (const float*)d_in[1];
  const float* wi = (const float*)d_in[2];
  const float* wo = (const float*)d_in[3];

  float* out        = (float*)d_out;
  float* out_logits = out + (size_t)NTOK * DM;
  float* out_idx    = out_logits + (size_t)NTOK * NE;

  char* w = (char*)d_ws;
  int*      meta      = (int*)w;                    // 4 KiB
  int*      expert_of = (int*)(w + 4096);           // 16 KiB
  float*    prob      = (float*)(w + 20480);        // 16 KiB
  int*      perm      = (int*)(w + 36864);          // 24 KiB
  float*    prob_g    = (float*)(w + 61440);        // 24 KiB
  ushort_t* Xg        = (ushort_t*)(w + 131072);    // 6144*768 bf16
  ushort_t* H         = Xg + (size_t)MAXR * DM;     // 6144*3072 bf16
  ushort_t* woT       = H + (size_t)MAXR * DF;      // 8*768*3072 bf16
  ushort_t* wiT       = woT + (size_t)NE * DM * DF; // 8*3072*768 bf16
  ushort_t* P         = wiT;                        // alias: wiT dead after GEMM1
  // total ws ~ 123 MB

  k_convT<<<dim3(DM / 128, DF / 128, NE), 256, 0, stream>>>(wi, wiT, DM, DF);
  k_convT<<<dim3(DF / 128, DM / 128, NE), 256, 0, stream>>>(wo, woT, DF, DM);
  k_router<<<NTOK / 4, 256, 0, stream>>>(X, Wr, out_logits, out_idx,
                                         expert_of, prob);
  k_scan<<<1, 64, 0, stream>>>(expert_of, prob, meta, perm, prob_g);
  k_copy<<<dim3(TM / 4, MAXTILES), 256, 0, stream>>>(X, meta, perm, Xg);
  k_gemm8<DM, DF, true><<<dim3(DF / 256, MAXTILES), 512, 0, stream>>>(
      Xg, wiT, meta, H);
  k_gemm8<DF, DM, false><<<dim3((DM / 256) * 4, MAXTILES), 512, 0, stream>>>(
      H, woT, meta, P);
  k_reduce<<<dim3(DM / 64, MAXTILES), 256, 0, stream>>>(P, meta, perm, prob_g, out);
}

// Round 9
// 153.309 us; speedup vs baseline: 1.4373x; 1.0933x over previous
//
#include <hip/hip_runtime.h>

// SwitchTransformers sparse MLP (top-1 MoE), MI355X/gfx950.
// Round 9: coalesced convT (was 64x scattered 16B stores/instr, ~90us for
// the pair). XOR-swizzled LDS transpose tile, 512B-span reads, 256B-span
// writes. Router/scan/copy/GEMM/reduce byte-identical to round 8.

typedef __attribute__((ext_vector_type(4))) float f32x4;
typedef __attribute__((ext_vector_type(8))) short short8;
typedef unsigned short ushort_t;
typedef unsigned int uint32;

#define DEVFN static __device__ __forceinline__
#define MFMA __builtin_amdgcn_mfma_f32_16x16x32_bf16

constexpr int NTOK = 4096;
constexpr int DM   = 768;
constexpr int DF   = 3072;
constexpr int NE   = 8;
constexpr int TM   = 256;                  // row-tile granule
constexpr int MAXTILES = NTOK / TM + NE;   // 24
constexpr int MAXR  = MAXTILES * TM;       // 6144
constexpr int BK    = 32;
constexpr int NKT   = 768 / BK;            // 24 K-steps per (split-)GEMM

// meta ints: [8..15] segStart, [16..23] seg_end, [24] nTiles,
// [64..87] tileExpert, [128..151] tileRow
DEVFN ushort_t f2bf(float f) {
  uint32 u = __float_as_uint(f);
  u += 0x7fffu + ((u >> 16) & 1u);
  return (ushort_t)(u >> 16);
}
DEVFN float bf2f(ushort_t u) { return __uint_as_float((uint32)u << 16); }

DEVFN void gl16(const void* g, void* l) {   // 16B/lane direct-to-LDS
  __builtin_amdgcn_global_load_lds(
      (const __attribute__((address_space(1))) void*)g,
      (__attribute__((address_space(3))) void*)l, 16, 0, 0);
}

// One wave per token: fp64 logits (argmax robustness), fp32 softmax
// computed redundantly on all lanes (no divergent fp64 exp, no atomics).
__global__ __launch_bounds__(256) void k_router(
    const float* __restrict__ X, const float* __restrict__ Wr,
    float* __restrict__ out_logits, float* __restrict__ out_idx,
    int* __restrict__ expert_of, float* __restrict__ prob) {
  int wid = threadIdx.x >> 6, lane = threadIdx.x & 63;
  int t = blockIdx.x * 4 + wid;
  const float* xrow = X + (size_t)t * DM;
  double acc[NE];
#pragma unroll
  for (int e = 0; e < NE; e++) acc[e] = 0.0;
  for (int d0 = 0; d0 < DM; d0 += 64) {
    int d = d0 + lane;
    float x = xrow[d];
    const float4* w4 = (const float4*)(Wr + (size_t)d * NE);
    float4 wa = w4[0], wb = w4[1];
    acc[0] += (double)x * wa.x; acc[1] += (double)x * wa.y;
    acc[2] += (double)x * wa.z; acc[3] += (double)x * wa.w;
    acc[4] += (double)x * wb.x; acc[5] += (double)x * wb.y;
    acc[6] += (double)x * wb.z; acc[7] += (double)x * wb.w;
  }
#pragma unroll
  for (int e = 0; e < NE; e++) {
#pragma unroll
    for (int s = 32; s > 0; s >>= 1) acc[e] += __shfl_xor(acc[e], s);
  }
#pragma unroll
  for (int e = 0; e < NE; e++)
    if (lane == e) out_logits[(size_t)t * NE + e] = (float)acc[e];
  double m = acc[0]; int idx = 0;
#pragma unroll
  for (int e = 1; e < NE; e++) if (acc[e] > m) { m = acc[e]; idx = e; }
  float s = 0.f;
#pragma unroll
  for (int e = 0; e < NE; e++) s += expf((float)(acc[e] - m));
  if (lane == 0) {
    out_idx[t] = (float)idx;
    expert_of[t] = idx;
    prob[t] = 1.f / s;
  }
}

// Single-block scan: per-group counts, per-expert exclusive scan, padded
// segment layout + tile table, stable-order scatter. Deterministic.
__global__ __launch_bounds__(64) void k_scan(
    const int* __restrict__ expert_of, const float* __restrict__ prob,
    int* __restrict__ meta, int* __restrict__ perm,
    float* __restrict__ prob_g) {
  __shared__ int exl[NTOK];
  int lane = threadIdx.x;
  const int4* src = (const int4*)expert_of;
  int4* dst = (int4*)exl;
#pragma unroll
  for (int j = 0; j < NTOK / 4 / 64; j++) dst[j * 64 + lane] = src[j * 64 + lane];
  __syncthreads();
  int cnt[NE];
#pragma unroll
  for (int e = 0; e < NE; e++) cnt[e] = 0;
  for (int j = 0; j < 64; j++) {
    int ex = exl[lane * 64 + j];
#pragma unroll
    for (int e = 0; e < NE; e++) cnt[e] += (ex == e);
  }
  int base[NE], tot[NE];
#pragma unroll
  for (int e = 0; e < NE; e++) {
    int inc = cnt[e];
#pragma unroll
    for (int s = 1; s < 64; s <<= 1) {
      int o = __shfl_up(inc, s);
      if (lane >= s) inc += o;
    }
    base[e] = inc - cnt[e];
    tot[e] = __shfl(inc, 63);
  }
  int segStart[NE];
  int pos = 0, nt = 0;
#pragma unroll
  for (int e = 0; e < NE; e++) {
    segStart[e] = pos;
    int tiles = (tot[e] + TM - 1) / TM;
    if (lane == 0) {
      meta[8 + e] = pos;
      meta[16 + e] = pos + tot[e];
      for (int i = 0; i < tiles; i++) {
        meta[64 + nt + i] = e;
        meta[128 + nt + i] = pos + i * TM;
      }
    }
    nt += tiles;
    pos += tiles * TM;
  }
  if (lane == 0) meta[24] = nt;
  int cum[NE];
#pragma unroll
  for (int e = 0; e < NE; e++) cum[e] = segStart[e] + base[e];
  for (int j = 0; j < 64; j++) {
    int t = lane * 64 + j;
    int ex = exl[lane * 64 + j];
    int p = 0;
#pragma unroll
    for (int e = 0; e < NE; e++) p += (ex == e) ? cum[e] : 0;
#pragma unroll
    for (int e = 0; e < NE; e++) cum[e] += (ex == e);
    perm[p] = t;
    prob_g[p] = prob[t];
  }
}

// Destination-indexed gather: Xg[r] = bf16(X[perm[r]]) for valid rows.
// Grid: (TM/4, MAXTILES) — tile on the slow dim (live-compact).
__global__ __launch_bounds__(256) void k_copy(
    const float* __restrict__ X, const int* __restrict__ meta,
    const int* __restrict__ perm, ushort_t* __restrict__ Xg) {
  int bt = blockIdx.y;
  if (bt >= meta[24]) return;
  int e = meta[64 + bt], row0 = meta[128 + bt], segEnd = meta[16 + e];
  int wid = threadIdx.x >> 6, lane = threadIdx.x & 63;
  int r = row0 + blockIdx.x * 4 + wid;
  if (r >= segEnd) return;
  int tok = perm[r];
  const float2* s2 = (const float2*)(X + (size_t)tok * DM);
  uint32* d2 = (uint32*)(Xg + (size_t)r * DM);
#pragma unroll
  for (int i = 0; i < DM / 128; i++) {
    float2 v = s2[i * 64 + lane];
    d2[i * 64 + lane] = (uint32)f2bf(v.x) | ((uint32)f2bf(v.y) << 16);
  }
}

// Convert + transpose: W [E][R][C] fp32 -> WT [E][C][R] bf16. 128x128 tile.
// Reads: 2 full 512B rows per wave-instr. LDS: T[c] row of 16 chunks, chunk
// XOR-swizzled (phys = q ^ (c&15)) -> bijective, b128-aligned. Writes: 4
// full 256B output rows per wave-instr.
__global__ __launch_bounds__(256) void k_convT(
    const float* __restrict__ W, ushort_t* __restrict__ WT, int R, int C) {
  __shared__ ushort_t T[128 * 128];
  int e = blockIdx.z;
  int r0 = blockIdx.x * 128, c0 = blockIdx.y * 128;
  const float* src = W + ((size_t)e * R + r0) * C + c0;
  int t = threadIdx.x;
  int rr = t >> 5, cc = (t & 31) * 4;
#pragma unroll
  for (int j = 0; j < 16; j++) {
    int r = rr + j * 8;
    float4 v = *(const float4*)(src + (size_t)r * C + cc);
#pragma unroll
    for (int i = 0; i < 4; i++) {
      int c = cc + i;
      T[c * 128 + (((r >> 3) ^ (c & 15)) << 3) + (r & 7)] =
          f2bf(((const float*)&v)[i]);
    }
  }
  __syncthreads();
  int q = t & 15, cb = t >> 4;
#pragma unroll
  for (int j = 0; j < 8; j++) {
    int c = cb + j * 16;
    short8 v = *(const short8*)&T[c * 128 + ((q ^ (c & 15)) << 3)];
    *(short8*)(WT + ((size_t)e * C + c0 + c) * R + r0 + q * 8) = v;
  }
}

// ---------------------------------------------------------------------------
// 8-wave 256x256 GEMM, BK=32, ring-4 LDS slots, counted vmcnt(8), 1 barrier
// per K-step, XOR bank swizzle on both operands. Per-wave output 128x64
// (wave grid 2Mx4N), acc[8][4] f32x4, 32 MFMA + 12 ds_read_b128 per K-step.
// Grid: y = row-tile (slow dim: dead blocks form a contiguous tail).
// FIRST: x = N-panel. !FIRST: x = panel*4 + z (split-K, koff = z*768).
// ---------------------------------------------------------------------------
template <int LDA, int NB, bool FIRST>
__global__ __launch_bounds__(512, 2) void k_gemm8(
    const ushort_t* __restrict__ A, const ushort_t* __restrict__ BT,
    const int* __restrict__ meta, ushort_t* __restrict__ Obf) {
  __shared__ short A_lds[4][256 * BK];
  __shared__ short B_lds[4][256 * BK];

  int bt = blockIdx.y;
  if (bt >= meta[24]) return;      // uniform exit before any barrier
  int e    = meta[64 + bt];
  int row0 = meta[128 + bt];
  int n0, koff, z;
  if constexpr (FIRST) {
    n0 = blockIdx.x * 256; koff = 0; z = 0;
  } else {
    n0 = (blockIdx.x >> 2) * 256; z = blockIdx.x & 3; koff = z * 768;
  }

  int tid = threadIdx.x, lane = tid & 63, w = tid >> 6;
  int wr = w >> 2, wc = w & 3;

  // Staging: thread -> row tid>>2, 16B slot tid&3 (linear LDS dest);
  // global source pre-swizzled: kslot_log = (lane&3) ^ ((lane>>3)&3).
  int srcSlot = (lane & 3) ^ ((lane >> 3) & 3);
  const ushort_t* aS = A + (size_t)(row0 + (tid >> 2)) * LDA + koff + srcSlot * 8;
  const ushort_t* bS = BT + ((size_t)e * NB + n0 + (tid >> 2)) * LDA + koff + srcSlot * 8;
  int dstOff = w * 512;   // wave-uniform LDS short offset (16 rows/wave/issue)

#define STAGE(sl, kt)                                                        \
  do {                                                                       \
    gl16(aS + (size_t)(kt) * BK, &A_lds[sl][dstOff]);                        \
    gl16(aS + (size_t)(kt) * BK + (size_t)128 * LDA, &A_lds[sl][dstOff + 4096]); \
    gl16(bS + (size_t)(kt) * BK, &B_lds[sl][dstOff]);                        \
    gl16(bS + (size_t)(kt) * BK + (size_t)128 * LDA, &B_lds[sl][dstOff + 4096]); \
  } while (0)

  // Swizzled read offsets: physical kslot = logical ^ ((row>>1)&3).
  int kslotRd = ((lane >> 4) ^ ((lane >> 1) & 3)) * 8;
  int aOff[8], bOff[4];
#pragma unroll
  for (int m = 0; m < 8; m++)
    aOff[m] = (wr * 128 + m * 16 + (lane & 15)) * BK + kslotRd;
#pragma unroll
  for (int n = 0; n < 4; n++)
    bOff[n] = (wc * 64 + n * 16 + (lane & 15)) * BK + kslotRd;

  f32x4 acc[8][4];
#pragma unroll
  for (int m = 0; m < 8; m++)
#pragma unroll
    for (int n = 0; n < 4; n++) acc[m][n] = (f32x4){0.f, 0.f, 0.f, 0.f};

  STAGE(0, 0); STAGE(1, 1); STAGE(2, 2);   // 12 loads in flight

#pragma unroll 4
  for (int t = 0; t < NKT; ++t) {
    __builtin_amdgcn_sched_barrier(0);
    asm volatile("s_waitcnt vmcnt(8)" ::: "memory");  // own slot-t loads done
    __builtin_amdgcn_s_barrier();                     // all waves' slot-t done;
    asm volatile("" ::: "memory");                    // all done reading t-1
    __builtin_amdgcn_sched_barrier(0);
    int tp = (t + 3 < NKT) ? t + 3 : t;               // dummy keeps vmcnt uniform
    STAGE((t + 3) & 3, tp);                           // (dead ring slot at tail)
    const short* aB = A_lds[t & 3];
    const short* bB = B_lds[t & 3];
    short8 af[8], bf[4];
#pragma unroll
    for (int m = 0; m < 8; m++) af[m] = *(const short8*)&aB[aOff[m]];
#pragma unroll
    for (int n = 0; n < 4; n++) bf[n] = *(const short8*)&bB[bOff[n]];
    __builtin_amdgcn_s_setprio(1);
#pragma unroll
    for (int m = 0; m < 8; m++)
#pragma unroll
      for (int n = 0; n < 4; n++)
        acc[m][n] = MFMA(af[m], bf[n], acc[m][n], 0, 0, 0);
    __builtin_amdgcn_s_setprio(0);
  }
#undef STAGE

  // C/D: col = lane&15, row = (lane>>4)*4 + r
  ushort_t* dst = FIRST ? Obf : Obf + (size_t)z * MAXR * NB;
#pragma unroll
  for (int m = 0; m < 8; m++) {
    int rowb = row0 + wr * 128 + m * 16 + (lane >> 4) * 4;
#pragma unroll
    for (int n = 0; n < 4; n++) {
      int col = n0 + wc * 64 + n * 16 + (lane & 15);
#pragma unroll
      for (int r = 0; r < 4; r++) {
        float v = acc[m][n][r];
        if (FIRST) v = v > 0.f ? v : 0.f;
        dst[(size_t)(rowb + r) * NB + col] = f2bf(v);
      }
    }
  }
}

// Reduce split-K partials, scale by prob, scatter to token rows.
// Grid: (DM/64, MAXTILES) — tile on the slow dim (live-compact).
__global__ __launch_bounds__(256) void k_reduce(
    const ushort_t* __restrict__ P, const int* __restrict__ meta,
    const int* __restrict__ perm, const float* __restrict__ prob_g,
    float* __restrict__ out) {
  int bt = blockIdx.y;
  if (bt >= meta[24]) return;
  int e = meta[64 + bt], row0 = meta[128 + bt], segEnd = meta[16 + e];
  int c0 = blockIdx.x * 64;
  int t = threadIdx.x;
  int col = c0 + (t & 7) * 8;
#pragma unroll
  for (int i = 0; i < 8; i++) {
    int r = row0 + (t >> 3) + i * 32;
    if (r >= segEnd) continue;
    int tok = perm[r];
    float p = prob_g[r];
    float s[8];
#pragma unroll
    for (int j = 0; j < 8; j++) s[j] = 0.f;
#pragma unroll
    for (int z = 0; z < 4; z++) {
      short8 v = *(const short8*)&P[((size_t)z * MAXR + r) * DM + col];
#pragma unroll
      for (int j = 0; j < 8; j++) s[j] += bf2f((ushort_t)v[j]);
    }
    float4 o0 = {p * s[0], p * s[1], p * s[2], p * s[3]};
    float4 o1 = {p * s[4], p * s[5], p * s[6], p * s[7]};
    *(float4*)&out[(size_t)tok * DM + col] = o0;
    *(float4*)&out[(size_t)tok * DM + col + 4] = o1;
  }
}

extern "C" void kernel_launch(void* const* d_in, const int* in_sizes, int n_in,
                              void* d_out, int out_size, void* d_ws, size_t ws_size,
                              hipStream_t stream) {
  const float* X  = (const float*)d_in[0];
  const float* Wr = (const float*)d_in[1];
  const float* wi = (const float*)d_in[2];
  const float* wo = (const float*)d_in[3];

  float* out        = (float*)d_out;
  float* out_logits = out + (size_t)NTOK * DM;
  float* out_idx    = out_logits + (size_t)NTOK * NE;

  char* w = (char*)d_ws;
  int*      meta      = (int*)w;                    // 4 KiB
  int*      expert_of = (int*)(w + 4096);           // 16 KiB
  float*    prob      = (float*)(w + 20480);        // 16 KiB
  int*      perm      = (int*)(w + 36864);          // 24 KiB
  float*    prob_g    = (float*)(w + 61440);        // 24 KiB
  ushort_t* Xg        = (ushort_t*)(w + 131072);    // 6144*768 bf16
  ushort_t* H         = Xg + (size_t)MAXR * DM;     // 6144*3072 bf16
  ushort_t* woT       = H + (size_t)MAXR * DF;      // 8*768*3072 bf16
  ushort_t* wiT       = woT + (size_t)NE * DM * DF; // 8*3072*768 bf16
  ushort_t* P         = wiT;                        // alias: wiT dead after GEMM1
  // total ws ~ 123 MB

  k_convT<<<dim3(DM / 128, DF / 128, NE), 256, 0, stream>>>(wi, wiT, DM, DF);
  k_convT<<<dim3(DF / 128, DM / 128, NE), 256, 0, stream>>>(wo, woT, DF, DM);
  k_router<<<NTOK / 4, 256, 0, stream>>>(X, Wr, out_logits, out_idx,
                                         expert_of, prob);
  k_scan<<<1, 64, 0, stream>>>(expert_of, prob, meta, perm, prob_g);
  k_copy<<<dim3(TM / 4, MAXTILES), 256, 0, stream>>>(X, meta, perm, Xg);
  k_gemm8<DM, DF, true><<<dim3(DF / 256, MAXTILES), 512, 0, stream>>>(
      Xg, wiT, meta, H);
  k_gemm8<DF, DM, false><<<dim3((DM / 256) * 4, MAXTILES), 512, 0, stream>>>(
      H, woT, meta, P);
  k_reduce<<<dim3(DM / 64, MAXTILES), 256, 0, stream>>>(P, meta, perm, prob_g, out);
}